// Round 4
// baseline (544.657 us; speedup 1.0000x reference)
//
#include <hip/hip_runtime.h>
#include <math.h>

namespace {
constexpr int DD = 2048;   // feature dim
constexpr int EE = 64;     // experts
constexpr int EB = 128;    // linear + noise outputs
constexpr int KK = 8;      // top-k
constexpr int TPB = 64;    // tokens per block
constexpr int KT = 32;     // K chunk
constexpr int NTHREADS = 256;
constexpr float TAU = 2e-4f;  // ambiguity gap threshold (>> 3-sigma fp32 GEMM error ~1e-5)
}

__global__ __launch_bounds__(NTHREADS, 2)
void noisy_topk_router(const float* __restrict__ x,
                       const float* __restrict__ noise,
                       const float* __restrict__ Wl,
                       const float* __restrict__ bl,
                       const float* __restrict__ Wn,
                       const float* __restrict__ bn,
                       float* __restrict__ out_router,
                       float* __restrict__ out_idx)
{
    __shared__ __align__(16) float xs[KT][TPB + 4];   // transposed x tile (rows 272B)
    __shared__ __align__(16) float ws[KT][EB + 4];    // transposed W tile (rows 528B)
    __shared__ __align__(16) float res[TPB][EB + 1];  // logits | noise_logits -> noisy
    __shared__ float tkv[TPB][KK];
    __shared__ int   tki[TPB][KK];
    __shared__ int   amb_list[TPB];
    __shared__ int   amb_count;

    const int tid = threadIdx.x;
    const int tx  = tid & 15;            // expert group: experts tx*8 .. tx*8+7
    const int ty  = tid >> 4;            // token group: tokens ty*4 .. ty*4+3
    const long tok0 = (long)blockIdx.x * TPB;

    float acc[4][8];
#pragma unroll
    for (int i = 0; i < 4; ++i)
#pragma unroll
        for (int j = 0; j < 8; ++j) acc[i][j] = 0.f;

    const int lt = tid >> 3;             // 0..31: row index for staging
    const int lk = tid & 7;              // 0..7: float4 index within 32-float chunk

    for (int k0 = 0; k0 < DD; k0 += KT) {
        __syncthreads();   // protect xs/ws from previous iteration's readers
#pragma unroll
        for (int p = 0; p < 2; ++p) {
            const int token = p * 32 + lt;
            const float4 v = *reinterpret_cast<const float4*>(
                &x[(tok0 + token) * (long)DD + k0 + lk * 4]);
            xs[lk * 4 + 0][token] = v.x;
            xs[lk * 4 + 1][token] = v.y;
            xs[lk * 4 + 2][token] = v.z;
            xs[lk * 4 + 3][token] = v.w;
        }
#pragma unroll
        for (int p = 0; p < 2; ++p) {
            const int row = p * 32 + lt;
            const float4 v = *reinterpret_cast<const float4*>(
                &Wl[(long)row * DD + k0 + lk * 4]);
            ws[lk * 4 + 0][row] = v.x;
            ws[lk * 4 + 1][row] = v.y;
            ws[lk * 4 + 2][row] = v.z;
            ws[lk * 4 + 3][row] = v.w;
        }
#pragma unroll
        for (int p = 0; p < 2; ++p) {
            const int row = p * 32 + lt;
            const float4 v = *reinterpret_cast<const float4*>(
                &Wn[(long)row * DD + k0 + lk * 4]);
            ws[lk * 4 + 0][EE + row] = v.x;
            ws[lk * 4 + 1][EE + row] = v.y;
            ws[lk * 4 + 2][EE + row] = v.z;
            ws[lk * 4 + 3][EE + row] = v.w;
        }
        __syncthreads();
#pragma unroll
        for (int kk = 0; kk < KT; ++kk) {
            const float4 xa = *reinterpret_cast<const float4*>(&xs[kk][ty * 4]);
            const float4 wa = *reinterpret_cast<const float4*>(&ws[kk][tx * 8]);
            const float4 wb = *reinterpret_cast<const float4*>(&ws[kk][tx * 8 + 4]);
            const float xv[4] = {xa.x, xa.y, xa.z, xa.w};
            const float wv[8] = {wa.x, wa.y, wa.z, wa.w, wb.x, wb.y, wb.z, wb.w};
#pragma unroll
            for (int i = 0; i < 4; ++i)
#pragma unroll
                for (int j = 0; j < 8; ++j)
                    acc[i][j] = fmaf(xv[i], wv[j], acc[i][j]);
        }
    }
    __syncthreads();

    // epilogue: logits / noise_logits (+bias) into res
#pragma unroll
    for (int j = 0; j < 8; ++j) {
        const int e = tx * 8 + j;
        const float bias = (e < EE) ? bl[e] : bn[e - EE];
#pragma unroll
        for (int i = 0; i < 4; ++i)
            res[ty * 4 + i][e] = acc[i][j] + bias;
    }
    if (tid == 0) amb_count = 0;
    __syncthreads();

    // noisy = logits + noise * softplus(noise_logits)
    {
        const int t  = tid >> 2;
        const int e0 = (tid & 3) * 16;
        const float* nrow = &noise[(tok0 + t) * (long)EE];
#pragma unroll 4
        for (int j = 0; j < 16; ++j) {
            const int e = e0 + j;
            const float z  = res[t][EE + e];
            const float sp = fmaxf(z, 0.f) + log1pf(expf(-fabsf(z)));
            res[t][e] = res[t][e] + nrow[e] * sp;
        }
    }
    __syncthreads();

    // top-9 extraction per token (threads 0..63); strict > keeps lowest index on ties
    if (tid < TPB) {
        const int t = tid;
        float lv[9]; int li[9];
#pragma unroll
        for (int k = 0; k < 9; ++k) {
            float best = -INFINITY;
            int bi = 0;
#pragma unroll 4
            for (int e = 0; e < EE; ++e) {
                const float v = res[t][e];
                if (v > best) { best = v; bi = e; }
            }
            res[t][bi] = -INFINITY;
            lv[k] = best; li[k] = bi;
        }
        bool amb = false;
#pragma unroll
        for (int k = 0; k < 8; ++k) amb |= (lv[k] - lv[k + 1] < TAU);
        // softmax over top-8 (max = lv[0])
        const float m = lv[0];
        float p[KK];
        float s = 0.f;
#pragma unroll
        for (int k = 0; k < KK; ++k) { p[k] = expf(lv[k] - m); s += p[k]; }
        const float inv = 1.f / s;
#pragma unroll
        for (int k = 0; k < KK; ++k) { tkv[t][k] = p[k] * inv; tki[t][k] = li[k]; }
        if (amb) { const int pos = atomicAdd(&amb_count, 1); amb_list[pos] = t; }
    }
    __syncthreads();

    // fp64 recompute of ambiguous tokens (near-tie in top-9 -> fp32 ordering unsafe)
    const int namb = amb_count;
    double* part = reinterpret_cast<double*>(&xs[0][0]);   // 256 doubles (xs is dead)
    double* dots = reinterpret_cast<double*>(&ws[0][0]);   // 128 doubles (ws is dead)
    for (int a = 0; a < namb; ++a) {
        const int t = amb_list[a];
        {
            const int e  = tid >> 1;
            const int kb = (tid & 1) * (DD / 2);
            const float* xr = &x[(tok0 + t) * (long)DD + kb];
            const float* wr = (e < EE) ? &Wl[(long)e * DD + kb]
                                       : &Wn[(long)(e - EE) * DD + kb];
            double a2 = 0.0;
            for (int k = 0; k < DD / 2; k += 4) {
                const float4 xv = *reinterpret_cast<const float4*>(&xr[k]);
                const float4 wv = *reinterpret_cast<const float4*>(&wr[k]);
                a2 = fma((double)xv.x, (double)wv.x, a2);
                a2 = fma((double)xv.y, (double)wv.y, a2);
                a2 = fma((double)xv.z, (double)wv.z, a2);
                a2 = fma((double)xv.w, (double)wv.w, a2);
            }
            part[tid] = a2;
        }
        __syncthreads();
        if (tid < EB) dots[tid] = part[2 * tid] + part[2 * tid + 1];
        __syncthreads();
        if (tid < EE) {   // wave 0: fp64 noisy + butterfly top-8 + fp64 softmax
            const double v  = dots[tid] + (double)bl[tid];
            const double z  = dots[EE + tid] + (double)bn[tid];
            const double sp = fmax(z, 0.0) + log1p(exp(-fabs(z)));
            double val = v + (double)noise[(tok0 + t) * (long)EE + tid] * sp;
            int    idx = tid;
            double sel[KK]; int sidx[KK];
#pragma unroll
            for (int k = 0; k < KK; ++k) {
                double mv = val; int mi = idx;
#pragma unroll
                for (int m = 1; m < 64; m <<= 1) {
                    const double ov = __shfl_xor(mv, m, 64);
                    const int    oi = __shfl_xor(mi, m, 64);
                    if (ov > mv || (ov == mv && oi < mi)) { mv = ov; mi = oi; }
                }
                sel[k] = mv; sidx[k] = mi;
                if (idx == mi) val = -INFINITY;
            }
            if (tid == 0) {
                const double mx = sel[0];
                double p[KK]; double s = 0.0;
#pragma unroll
                for (int k = 0; k < KK; ++k) { p[k] = exp(sel[k] - mx); s += p[k]; }
                const double inv = 1.0 / s;
#pragma unroll
                for (int k = 0; k < KK; ++k) {
                    tkv[t][k] = (float)(p[k] * inv);
                    tki[t][k] = sidx[k];
                }
            }
        }
        __syncthreads();
    }

    // router output: compare-select scatter, coalesced float4 stores
    {
        const int t  = tid >> 2;
        const int e0 = (tid & 3) * 16;
        int   ki[KK];
        float kv[KK];
#pragma unroll
        for (int k = 0; k < KK; ++k) { ki[k] = tki[t][k]; kv[k] = tkv[t][k]; }
        float4 v[4];
        float* vf = reinterpret_cast<float*>(v);
#pragma unroll
        for (int j = 0; j < 16; ++j) {
            float val = 0.f;
#pragma unroll
            for (int k = 0; k < KK; ++k)
                val = (ki[k] == e0 + j) ? kv[k] : val;
            vf[j] = val;
        }
        float4* dst = reinterpret_cast<float4*>(&out_router[(tok0 + t) * (long)EE + e0]);
#pragma unroll
        for (int q = 0; q < 4; ++q) dst[q] = v[q];
    }
    // indices output, written as float32 values (whole d_out read as f32 by harness)
    {
        const int f = tid * 2;
        const int t = f >> 3;
        const int k0i = f & 7;
        out_idx[(tok0 + t) * (long)KK + k0i]     = (float)tki[t][k0i];
        out_idx[(tok0 + t) * (long)KK + k0i + 1] = (float)tki[t][k0i + 1];
    }
}

extern "C" void kernel_launch(void* const* d_in, const int* in_sizes, int n_in,
                              void* d_out, int out_size, void* d_ws, size_t ws_size,
                              hipStream_t stream) {
    const float* x     = (const float*)d_in[0];
    const float* noise = (const float*)d_in[1];
    const float* Wl    = (const float*)d_in[2];
    const float* bl    = (const float*)d_in[3];
    const float* Wn    = (const float*)d_in[4];
    const float* bn    = (const float*)d_in[5];

    const int M = in_sizes[0] / DD;            // B*S = 32768
    float* out_router = (float*)d_out;
    float* out_idx    = (float*)d_out + (long)M * EE;

    dim3 grid(M / TPB);
    dim3 block(NTHREADS);
    hipLaunchKernelGGL(noisy_topk_router, grid, block, 0, stream,
                       x, noise, Wl, bl, Wn, bn, out_router, out_idx);
}

// Round 5
// 372.863 us; speedup vs baseline: 1.4607x; 1.4607x over previous
//
#include <hip/hip_runtime.h>
#include <hip/hip_bf16.h>
#include <math.h>

namespace {
constexpr int DD = 2048;          // feature dim
constexpr int EE = 64;            // experts
constexpr int EB = 128;           // linear + noise outputs
constexpr int KK = 8;             // top-k
constexpr int TPB = 64;           // tokens per block
constexpr int NTH = 256;          // 4 waves
constexpr int KSTEPS = DD / 32;   // 64
constexpr float TAU = 2e-4f;      // ambiguity gap threshold (~50 sigma of split-bf16 error)
}

typedef __attribute__((ext_vector_type(8))) short short8;   // 8 bf16 (4 VGPRs)
typedef __attribute__((ext_vector_type(4))) float f32x4;

#define RES(t, e) res[(t) * (EB + 1) + (e)]

__device__ inline void split_bf16(float v, ushort& h, ushort& l) {
    __hip_bfloat16 hb = __float2bfloat16(v);
    float hf = __bfloat162float(hb);
    __hip_bfloat16 lb = __float2bfloat16(v - hf);
    h = __builtin_bit_cast(ushort, hb);
    l = __builtin_bit_cast(ushort, lb);
}

// Pack W_linear||W_noise into MFMA B-fragment order in workspace:
// ws layout (ushort): [s(64)][et(8)][hl(2)][lane(64)][i(8)]
// element: B[k][e] = W[e][k], e = et*16 + (lane&15), k = s*32 + (lane>>4)*8 + i
__global__ __launch_bounds__(256)
void prep_w(const float* __restrict__ Wl, const float* __restrict__ Wn,
            ushort* __restrict__ wsB)
{
    const int t    = blockIdx.x * 256 + threadIdx.x;    // 0..32767
    const int lane = t & 63;
    const int et   = (t >> 6) & 7;
    const int s    = t >> 9;                            // 0..63
    const int e    = et * 16 + (lane & 15);
    const int k    = s * 32 + ((lane >> 4) * 8);
    const float* src = (e < EE) ? &Wl[(long)e * DD + k] : &Wn[(long)(e - EE) * DD + k];
    const float4 f0 = *reinterpret_cast<const float4*>(src);
    const float4 f1 = *reinterpret_cast<const float4*>(src + 4);
    const float f[8] = {f0.x, f0.y, f0.z, f0.w, f1.x, f1.y, f1.z, f1.w};
    uint hw[4], lw[4];
#pragma unroll
    for (int j = 0; j < 4; ++j) {
        ushort h0, l0, h1, l1;
        split_bf16(f[2 * j], h0, l0);
        split_bf16(f[2 * j + 1], h1, l1);
        hw[j] = (uint)h0 | ((uint)h1 << 16);
        lw[j] = (uint)l0 | ((uint)l1 << 16);
    }
    const size_t chunk = ((size_t)(s * 8 + et)) * 1024;   // ushort units per (s,et): 2*512
    *reinterpret_cast<uint4*>(&wsB[chunk + lane * 8])       = make_uint4(hw[0], hw[1], hw[2], hw[3]);
    *reinterpret_cast<uint4*>(&wsB[chunk + 512 + lane * 8]) = make_uint4(lw[0], lw[1], lw[2], lw[3]);
}

__global__ __launch_bounds__(NTH, 2)
void router_main(const float* __restrict__ x,
                 const float* __restrict__ noise,
                 const ushort* __restrict__ wsB,
                 const float* __restrict__ Wl, const float* __restrict__ bl,
                 const float* __restrict__ Wn, const float* __restrict__ bn,
                 float* __restrict__ out_router, float* __restrict__ out_idx)
{
    // union region: [2][16384]B B-frag double buffer  -->  res[64][129] f32 + part/dots
    __shared__ __align__(16) unsigned char smem[36096];
    __shared__ float tkv[TPB][KK];
    __shared__ int   tki[TPB][KK];
    __shared__ int   amb_list[TPB];
    __shared__ int   amb_count;

    const int tid  = threadIdx.x;
    const int lane = tid & 63;
    const int wv   = tid >> 6;                 // wave 0..3, 16 tokens each
    const long tok0 = (long)blockIdx.x * TPB;

    if (tid == 0) amb_count = 0;

    // ---------------- split-bf16 MFMA GEMM ----------------
    f32x4 acc[8];
#pragma unroll
    for (int i = 0; i < 8; ++i) acc[i] = {0.f, 0.f, 0.f, 0.f};

    // A: lane holds x[tok0 + wv*16 + (lane&15)][k0 + (lane>>4)*8 + i], i=0..7
    const float* aptr = x + (tok0 + wv * 16 + (lane & 15)) * (long)DD + ((lane >> 4) * 8);
    const uint4* wsrc = reinterpret_cast<const uint4*>(wsB);   // 1024 uint4 per K-step

    // prologue: stage W(0) into buf0, load A(0)
    float4 aA = *reinterpret_cast<const float4*>(aptr);
    float4 aB = *reinterpret_cast<const float4*>(aptr + 4);
    {
        uint4* b0 = reinterpret_cast<uint4*>(smem);
        b0[tid]       = wsrc[tid];
        b0[256 + tid] = wsrc[256 + tid];
        b0[512 + tid] = wsrc[512 + tid];
        b0[768 + tid] = wsrc[768 + tid];
    }
    __syncthreads();

    for (int s = 0; s < KSTEPS; ++s) {
        float4 pA, pB;
        uint4 n0, n1, n2, n3;
        const bool hasNext = (s + 1 < KSTEPS);
        if (hasNext) {                         // issue prefetch loads first (hide latency)
            const float* ap = aptr + (s + 1) * 32;
            pA = *reinterpret_cast<const float4*>(ap);
            pB = *reinterpret_cast<const float4*>(ap + 4);
            const uint4* wp = wsrc + (size_t)(s + 1) * 1024;
            n0 = wp[tid]; n1 = wp[256 + tid]; n2 = wp[512 + tid]; n3 = wp[768 + tid];
        }
        // convert A(s) to hi/lo bf16 fragments
        short8 ahi, alo;
        {
            const float f[8] = {aA.x, aA.y, aA.z, aA.w, aB.x, aB.y, aB.z, aB.w};
#pragma unroll
            for (int i = 0; i < 8; ++i) {
                ushort h, l;
                split_bf16(f[i], h, l);
                ahi[i] = (short)h;
                alo[i] = (short)l;
            }
        }
        const char* bp = reinterpret_cast<const char*>(smem) + (s & 1) * 16384;
#pragma unroll
        for (int et = 0; et < 8; ++et) {
            const short8 bhi = *reinterpret_cast<const short8*>(bp + et * 2048 + lane * 16);
            const short8 blo = *reinterpret_cast<const short8*>(bp + et * 2048 + 1024 + lane * 16);
            acc[et] = __builtin_amdgcn_mfma_f32_16x16x32_bf16(ahi, bhi, acc[et], 0, 0, 0);
            acc[et] = __builtin_amdgcn_mfma_f32_16x16x32_bf16(alo, bhi, acc[et], 0, 0, 0);
            acc[et] = __builtin_amdgcn_mfma_f32_16x16x32_bf16(ahi, blo, acc[et], 0, 0, 0);
        }
        if (hasNext) {                         // write next buffer (other half; safe pre-barrier)
            uint4* bdst = reinterpret_cast<uint4*>(smem + ((s + 1) & 1) * 16384);
            bdst[tid]       = n0;
            bdst[256 + tid] = n1;
            bdst[512 + tid] = n2;
            bdst[768 + tid] = n3;
            aA = pA; aB = pB;
        }
        __syncthreads();
    }

    // ---------------- epilogue (res aliases dead B-buffers) ----------------
    float* res = reinterpret_cast<float*>(smem);         // [64][129]
    {
        // C/D layout: col = lane&15 (expert), row = (lane>>4)*4 + reg (token)
        const int col = lane & 15;
        const int rg  = (lane >> 4) * 4;
#pragma unroll
        for (int et = 0; et < 8; ++et) {
            const int e = et * 16 + col;
            const float bias = (et < 4) ? bl[e] : bn[e - EE];
#pragma unroll
            for (int r = 0; r < 4; ++r)
                RES(wv * 16 + rg + r, e) = acc[et][r] + bias;
        }
    }
    __syncthreads();

    // noisy = logits + noise * softplus(noise_logits)
    {
        const int t  = tid >> 2;
        const int e0 = (tid & 3) * 16;
        const float* nrow = &noise[(tok0 + t) * (long)EE];
#pragma unroll 4
        for (int j = 0; j < 16; ++j) {
            const int e = e0 + j;
            const float z  = RES(t, EE + e);
            const float sp = fmaxf(z, 0.f) + log1pf(expf(-fabsf(z)));
            RES(t, e) = RES(t, e) + nrow[e] * sp;
        }
    }
    __syncthreads();

    // top-9 extraction per token (threads 0..63); strict > keeps lowest index on ties
    if (tid < TPB) {
        const int t = tid;
        float lv[9]; int li[9];
#pragma unroll
        for (int k = 0; k < 9; ++k) {
            float best = -INFINITY;
            int bi = 0;
#pragma unroll 4
            for (int e = 0; e < EE; ++e) {
                const float v = RES(t, e);
                if (v > best) { best = v; bi = e; }
            }
            RES(t, bi) = -INFINITY;
            lv[k] = best; li[k] = bi;
        }
        bool amb = false;
#pragma unroll
        for (int k = 0; k < 8; ++k) amb |= (lv[k] - lv[k + 1] < TAU);
        const float m = lv[0];
        float p[KK];
        float sm = 0.f;
#pragma unroll
        for (int k = 0; k < KK; ++k) { p[k] = expf(lv[k] - m); sm += p[k]; }
        const float inv = 1.f / sm;
#pragma unroll
        for (int k = 0; k < KK; ++k) { tkv[t][k] = p[k] * inv; tki[t][k] = li[k]; }
        if (amb) { const int pos = atomicAdd(&amb_count, 1); amb_list[pos] = t; }
    }
    __syncthreads();

    // fp64 recompute of ambiguous tokens (near-tie -> split-bf16 ordering unsafe)
    const int namb = amb_count;
    double* part = reinterpret_cast<double*>(smem + 33024);   // 256 doubles
    double* dots = reinterpret_cast<double*>(smem + 35072);   // 128 doubles
    for (int a = 0; a < namb; ++a) {
        const int t = amb_list[a];
        {
            const int e  = tid >> 1;
            const int kb = (tid & 1) * (DD / 2);
            const float* xr = &x[(tok0 + t) * (long)DD + kb];
            const float* wr = (e < EE) ? &Wl[(long)e * DD + kb]
                                       : &Wn[(long)(e - EE) * DD + kb];
            double a2 = 0.0;
            for (int k = 0; k < DD / 2; k += 4) {
                const float4 xv = *reinterpret_cast<const float4*>(&xr[k]);
                const float4 wv = *reinterpret_cast<const float4*>(&wr[k]);
                a2 = fma((double)xv.x, (double)wv.x, a2);
                a2 = fma((double)xv.y, (double)wv.y, a2);
                a2 = fma((double)xv.z, (double)wv.z, a2);
                a2 = fma((double)xv.w, (double)wv.w, a2);
            }
            part[tid] = a2;
        }
        __syncthreads();
        if (tid < EB) dots[tid] = part[2 * tid] + part[2 * tid + 1];
        __syncthreads();
        if (tid < EE) {   // wave 0: fp64 noisy + butterfly top-8 + fp64 softmax
            const double v  = dots[tid] + (double)bl[tid];
            const double z  = dots[EE + tid] + (double)bn[tid];
            const double sp = fmax(z, 0.0) + log1p(exp(-fabs(z)));
            double val = v + (double)noise[(tok0 + t) * (long)EE + tid] * sp;
            int    idx = tid;
            double sel[KK]; int sidx[KK];
#pragma unroll
            for (int k = 0; k < KK; ++k) {
                double mv = val; int mi = idx;
#pragma unroll
                for (int m = 1; m < 64; m <<= 1) {
                    const double ov = __shfl_xor(mv, m, 64);
                    const int    oi = __shfl_xor(mi, m, 64);
                    if (ov > mv || (ov == mv && oi < mi)) { mv = ov; mi = oi; }
                }
                sel[k] = mv; sidx[k] = mi;
                if (idx == mi) val = -INFINITY;
            }
            if (tid == 0) {
                const double mx = sel[0];
                double p[KK]; double sm = 0.0;
#pragma unroll
                for (int k = 0; k < KK; ++k) { p[k] = exp(sel[k] - mx); sm += p[k]; }
                const double inv = 1.0 / sm;
#pragma unroll
                for (int k = 0; k < KK; ++k) {
                    tkv[t][k] = (float)(p[k] * inv);
                    tki[t][k] = sidx[k];
                }
            }
        }
        __syncthreads();
    }

    // router output: compare-select scatter, coalesced float4 stores
    {
        const int t  = tid >> 2;
        const int e0 = (tid & 3) * 16;
        int   ki[KK];
        float kv[KK];
#pragma unroll
        for (int k = 0; k < KK; ++k) { ki[k] = tki[t][k]; kv[k] = tkv[t][k]; }
        float4 v[4];
        float* vf = reinterpret_cast<float*>(v);
#pragma unroll
        for (int j = 0; j < 16; ++j) {
            float val = 0.f;
#pragma unroll
            for (int k = 0; k < KK; ++k)
                val = (ki[k] == e0 + j) ? kv[k] : val;
            vf[j] = val;
        }
        float4* dst = reinterpret_cast<float4*>(&out_router[(tok0 + t) * (long)EE + e0]);
#pragma unroll
        for (int q = 0; q < 4; ++q) dst[q] = v[q];
    }
    // indices output, written as float32 values (whole d_out read as f32 by harness)
    {
        const int f = tid * 2;
        const int t = f >> 3;
        const int k0i = f & 7;
        out_idx[(tok0 + t) * (long)KK + k0i]     = (float)tki[t][k0i];
        out_idx[(tok0 + t) * (long)KK + k0i + 1] = (float)tki[t][k0i + 1];
    }
}

extern "C" void kernel_launch(void* const* d_in, const int* in_sizes, int n_in,
                              void* d_out, int out_size, void* d_ws, size_t ws_size,
                              hipStream_t stream) {
    const float* x     = (const float*)d_in[0];
    const float* noise = (const float*)d_in[1];
    const float* Wl    = (const float*)d_in[2];
    const float* bl    = (const float*)d_in[3];
    const float* Wn    = (const float*)d_in[4];
    const float* bn    = (const float*)d_in[5];

    const int M = in_sizes[0] / DD;            // B*S = 32768
    float* out_router = (float*)d_out;
    float* out_idx    = (float*)d_out + (long)M * EE;
    ushort* wsB = (ushort*)d_ws;               // 1 MiB fragment-packed W hi/lo

    hipLaunchKernelGGL(prep_w, dim3(128), dim3(256), 0, stream, Wl, Wn, wsB);
    hipLaunchKernelGGL(router_main, dim3(M / TPB), dim3(NTH), 0, stream,
                       x, noise, wsB, Wl, bl, Wn, bn, out_router, out_idx);
}